// Round 12
// baseline (104.137 us; speedup 1.0000x reference)
//
#include <hip/hip_runtime.h>

#define UNITS 14336
#define IN_F 4096
#define PACKED 1024
#define CLIP_VAL 100.0f

typedef unsigned int uint32;

using bf16x8 = __attribute__((ext_vector_type(8))) short;   // 8 bf16 = 4 VGPRs
using f32x4  = __attribute__((ext_vector_type(4))) float;   // 4 fp32 acc

// fp32 -> bf16 round-to-nearest-even
__device__ inline unsigned short f2bf(float f) {
    uint32 u = __float_as_uint(f);
    u += 0x7FFFu + ((u >> 16) & 1u);
    return (unsigned short)(u >> 16);
}

__device__ inline uint32 pack2bf(float a, float b) {
    return (uint32)f2bf(a) | ((uint32)f2bf(b) << 16);
}

// SWAR unpack: one packed byte (value 0..255, 4 crumbs little-endian)
// -> two uint32, each holding 2 bf16: r0 = {bf(c0), bf(c1)}, r1 = {bf(c2), bf(c3)}.
// crumb->bf16: 0->0x0000, 1->0x3F80 (+1), 2->0xBF80 (-1), 3->0x8000 (-0.0, harmless in MAC)
__device__ inline void unpack_byte(uint32 v, uint32& r0, uint32& r1) {
    uint32 t0 = (v & 3u) | ((v & 0xCu) << 14);         // c0 @ [1:0], c1 @ [17:16]
    uint32 t1 = ((v >> 4) & 3u) | ((v & 0xC0u) << 10); // c2, c3
    uint32 s0 = t0 >> 1;
    uint32 s1 = t1 >> 1;
    uint32 nz0 = (t0 ^ s0) & 0x00010001u;
    uint32 nz1 = (t1 ^ s1) & 0x00010001u;
    r0 = nz0 * 0x3F80u + ((s0 & 0x00010001u) << 15);
    r1 = nz1 * 0x3F80u + ((s1 & 0x00010001u) << 15);
}

__device__ inline float clipf(float y) {
    return fminf(fmaxf(y, -CLIP_VAL), CLIP_VAL);
}

// k-permuted fragment layout (unchanged):
// "group" g in [0,64) covers original k in [g*64, g*64+64).
// Within a group, lane quad q and k-step s in {0,1}:
//   MFMA k-slot q*8+j  <->  original k = g*64 + q*16 + s*8 + j
// pw side: lane(q,n) needs compacted dword c = g*4+q of unit row n
//   (original int32 elements 4c..4c+3; bytes 0,1 -> step s=0, 2,3 -> s=1).
// x side: granule idx = g*256 + s*128 + h*64 + lane holds 8 bf16:
//   j -> x[h*16 + (lane&15)][g*64 + (lane>>4)*16 + s*8 + j]

// Kernel 1: convert x [32][4096] fp32 -> bf16 in permuted A-fragment order.
__global__ __launch_bounds__(256) void convert_x_kernel(
    const float* __restrict__ x, uint4* __restrict__ ws) {
    int t = blockIdx.x * 256 + threadIdx.x;      // 0..16383 = granule idx
    int lane = t & 63;
    int h = (t >> 6) & 1;
    int s = (t >> 7) & 1;
    int g = t >> 8;
    int n = lane & 15;
    int q = lane >> 4;
    int b = h * 16 + n;
    int k0 = g * 64 + q * 16 + s * 8;
    const float4* src = (const float4*)(x + (size_t)b * IN_F + k0);
    float4 lo = src[0];
    float4 hi = src[1];
    uint4 o;
    o.x = pack2bf(lo.x, lo.y);
    o.y = pack2bf(lo.z, lo.w);
    o.z = pack2bf(hi.x, hi.y);
    o.w = pack2bf(hi.z, hi.w);
    ws[t] = o;
}

// Kernel 2: MFMA GEMM, v12 — BARRIER-FREE self-staged pipeline.
//
// R9/R11 showed the stage->__syncthreads->compute alternation dilutes the HBM
// stream to ~3.6 TB/s (memory pipe idle during compute phases). Fix: each
// wave stages exactly the pw data it later reads — wave wid owns compacted
// dword columns [wid*32, wid*32+32) of all 16 tile rows (= its K-range
// groups [wid*8, wid*8+8)). Stage = 8 global uint4 loads (4 rows x 256 B
// contiguous segments per instruction) + in-register int32->byte compaction
// (3 VALU/dword) + 8 ds_write_b32. Ordering vs the wave's own ds_reads is
// wave-local lgkmcnt — NO block barrier before the K-loop, so the 32
// resident waves/CU stay phase-staggered and the memory pipe never idles.
// In-register compaction also shrinks the LDS tile 64 KB -> 16.6 KB.
// Bank math (32 banks, addr/4 mod 32): row stride 1040 B = 260 dwords,
// 260 mod 32 = 4 -> read (iter i, lane q,n): bank = (4n + q + const) mod 32
// = 2 lanes/bank = free (m136); writes likewise <=2-way.
// Grid: 896 blocks x 512 threads (8 waves), tile 16 units x 32 batches,
// K-split 8. LDS 16.6 + 16 KB -> threads cap 4 blocks/CU, 32 waves/CU.
__global__ __launch_bounds__(512, 8) void ternary_mm_kernel(
    const uint4* __restrict__ xw,     // permuted bf16 x fragments
    const int*   __restrict__ pw,     // [UNITS][PACKED] packed bytes as int32
    const float* __restrict__ scale,
    const float* __restrict__ bias,
    float*       __restrict__ out) {
    __shared__ char  stg[16 * 1040];  // compacted pw tile, swizzle stride 1040
    __shared__ f32x4 red[8][2][64];   // [wave][h][lane] = 16 KB

    const int tid  = threadIdx.x;
    const int wid  = tid >> 6;           // 0..7 = K-split index
    const int lane = tid & 63;
    const int q    = lane >> 4;          // quad 0..3 (also 'a' in stage map)
    const int n    = lane & 15;          // row-in-tile (also 'b' in stage map)
    const int u0   = blockIdx.x << 4;    // 16 units per block
    const int g0   = wid << 3;           // first group (of 64 total)

    // ---- self-stage this wave's pw slice: rows 0-15 x dword cols [wid*32,+32)
    {
        const char* src = (const char*)pw;
        #pragma unroll
        for (int j = 0; j < 8; ++j) {
            const int j2 = j >> 1;           // row quad 0..3
            const int hh = j & 1;            // column half 0..1
            const int row = (j2 << 2) + q;   // 4 rows per instruction
            const int cc  = (wid << 5) + (hh << 4) + n;   // compacted dword idx
            uint4 v = *(const uint4*)(src + (size_t)(u0 + row) * 4096
                                          + ((size_t)cc << 4));
            uint32 d = (v.x & 0xFFu) | ((v.y & 0xFFu) << 8)
                     | ((v.z & 0xFFu) << 16) | ((v.w & 0xFFu) << 24);
            *(uint32*)(stg + row * 1040 + (cc << 2)) = d;
        }
    }
    // NO __syncthreads: each wave reads only what it wrote (lgkmcnt-ordered).

    const uint4* xb = xw + (g0 << 8) + lane;
    const char*  lb = stg + n * 1040 + (((wid << 5) + q) << 2);

    f32x4 acc0 = {0.f,0.f,0.f,0.f};      // batches h0 (0-15)
    f32x4 acc1 = {0.f,0.f,0.f,0.f};      // batches h1 (16-31)

    #pragma unroll
    for (int i = 0; i < 8; ++i) {
        uint4 x00 = xb[(i << 8)];            // s=0, h=0
        uint4 x01 = xb[(i << 8) + 64];       // s=0, h=1
        uint4 x10 = xb[(i << 8) + 128];      // s=1, h=0
        uint4 x11 = xb[(i << 8) + 192];      // s=1, h=1
        uint32 w = *(const uint32*)(lb + (i << 4));   // ds_read_b32, 2-way free

        uint4 fA, fB;                        // step 0 / step 1 weight frags
        unpack_byte(w & 0xFFu,         fA.x, fA.y);
        unpack_byte((w >> 8) & 0xFFu,  fA.z, fA.w);
        unpack_byte((w >> 16) & 0xFFu, fB.x, fB.y);
        unpack_byte(w >> 24,           fB.z, fB.w);
        bf16x8 vA = __builtin_bit_cast(bf16x8, fA);
        bf16x8 vB = __builtin_bit_cast(bf16x8, fB);

        acc0 = __builtin_amdgcn_mfma_f32_16x16x32_bf16(
            __builtin_bit_cast(bf16x8, x00), vA, acc0, 0, 0, 0);
        acc1 = __builtin_amdgcn_mfma_f32_16x16x32_bf16(
            __builtin_bit_cast(bf16x8, x01), vA, acc1, 0, 0, 0);
        acc0 = __builtin_amdgcn_mfma_f32_16x16x32_bf16(
            __builtin_bit_cast(bf16x8, x10), vB, acc0, 0, 0, 0);
        acc1 = __builtin_amdgcn_mfma_f32_16x16x32_bf16(
            __builtin_bit_cast(bf16x8, x11), vB, acc1, 0, 0, 0);
    }

    red[wid][0][lane] = acc0;
    red[wid][1][lane] = acc1;
    __syncthreads();

    // Reduce 8 K-partials + epilogue. 128 active threads, one per (h, lane).
    if (tid < 128) {
        const int h = tid >> 6;
        const int l = tid & 63;
        f32x4 s = red[0][h][l];
        #pragma unroll
        for (int w = 1; w < 8; ++w) {
            f32x4 v = red[w][h][l];
            s[0] += v[0]; s[1] += v[1]; s[2] += v[2]; s[3] += v[3];
        }
        const int u  = u0 + (l & 15);
        const int b0 = h * 16 + ((l >> 4) << 2);   // row = (lane>>4)*4 + reg
        const float sc = scale[u];
        const float bi = bias[u];
        float* o = out + (size_t)b0 * UNITS + u;
        o[0 * UNITS] = clipf(s[0] * sc + bi);
        o[1 * UNITS] = clipf(s[1] * sc + bi);
        o[2 * UNITS] = clipf(s[2] * sc + bi);
        o[3 * UNITS] = clipf(s[3] * sc + bi);
    }
}

extern "C" void kernel_launch(void* const* d_in, const int* in_sizes, int n_in,
                              void* d_out, int out_size, void* d_ws, size_t ws_size,
                              hipStream_t stream) {
    const float* x     = (const float*)d_in[0];
    const int*   pw    = (const int*)d_in[1];
    const float* scale = (const float*)d_in[2];
    const float* bias  = (const float*)d_in[3];
    float* out = (float*)d_out;

    // ws usage: 32*4096 bf16 = 256 KB permuted x fragments (single copy)
    uint4* xw = (uint4*)d_ws;

    convert_x_kernel<<<64, 256, 0, stream>>>(x, xw);
    ternary_mm_kernel<<<UNITS / 16, 512, 0, stream>>>(xw, pw, scale, bias, out);
}